// Round 1
// baseline (15291.907 us; speedup 1.0000x reference)
//
#include <hip/hip_runtime.h>
#include <hip/hip_bf16.h>
#include <math.h>

// Problem constants
#define BB 16
#define SS 128
#define TT 64
#define EE 768
#define HH 1024
#define H4 4096
#define VV 32000
#define E2 1536

// ---------------------------------------------------------------------------
// 32x32 tiled transpose: dst[c][r] = src[r][c]
// ---------------------------------------------------------------------------
__global__ __launch_bounds__(256) void transpose_k(const float* __restrict__ src,
                                                   float* __restrict__ dst,
                                                   int R, int C) {
  __shared__ float t[32][33];
  int bx = blockIdx.x * 32;  // col tile
  int by = blockIdx.y * 32;  // row tile
  int x = threadIdx.x;       // 0..31
  for (int y = threadIdx.y; y < 32; y += 8)
    t[y][x] = src[(size_t)(by + y) * C + bx + x];
  __syncthreads();
  for (int y = threadIdx.y; y < 32; y += 8)
    dst[(size_t)(bx + y) * R + by + x] = t[x][y];
}

// ---------------------------------------------------------------------------
// Generic small-M GEMM: C[16-row tile] = A @ W^T  (W is (N,K) row-major)
// Supports two operand sets (A1,W1)+(A2,W2) selected via blockIdx.z, each
// K-split ns1/ns2 ways -> writes partial buffer P[z][16][N] when partial=1.
// Full mode (grid.z==1): C[(mo+b)*ldc + col] = acc + bias1 + bias2.
// Block: 256 threads. Tile: 16 rows x 64 cols. K chunk: 64.
// ---------------------------------------------------------------------------
__global__ __launch_bounds__(256) void gemm16(
    const float* __restrict__ A1, int lda1, int K1, const float* __restrict__ W1, int ldw1, int ns1,
    const float* __restrict__ A2, int lda2, int K2, const float* __restrict__ W2, int ldw2, int ns2,
    const float* __restrict__ bias1, const float* __restrict__ bias2,
    float* __restrict__ C, int ldc, int N, int partial) {
  int nb = blockIdx.x * 64;
  int mo = blockIdx.y * 16;
  int z = blockIdx.z;
  const float* A;
  const float* W;
  int lda, ldw, kbase, klen;
  if (z < ns1) {
    A = A1; lda = lda1; W = W1; ldw = ldw1;
    klen = K1 / ns1; kbase = z * klen;
  } else {
    int zz = z - ns1;
    A = A2; lda = lda2; W = W2; ldw = ldw2;
    klen = K2 / ns2; kbase = zz * klen;
  }
  A += (size_t)mo * lda;

  __shared__ float Al[16][65];   // [row][k]
  __shared__ float Wt[64][68];   // transposed: [k][col], pad keeps 16B align

  int tid = threadIdx.x;
  int b = tid >> 4;             // 0..15 row
  int jq = (tid & 15) << 2;     // 0,4,...,60 col group
  float4 acc = {0.f, 0.f, 0.f, 0.f};

  for (int kc = 0; kc < klen; kc += 64) {
    int k0 = kbase + kc;
    for (int idx = tid; idx < 16 * 64; idx += 256) {
      int r = idx >> 6, cc = idx & 63;
      Al[r][cc] = A[(size_t)r * lda + k0 + cc];
    }
    for (int idx = tid; idx < 64 * 64; idx += 256) {
      int r = idx >> 6, cc = idx & 63;
      Wt[cc][r] = W[(size_t)(nb + r) * ldw + k0 + cc];
    }
    __syncthreads();
#pragma unroll 16
    for (int k = 0; k < 64; ++k) {
      float a = Al[b][k];
      float4 w = *(const float4*)&Wt[k][jq];
      acc.x += a * w.x;
      acc.y += a * w.y;
      acc.z += a * w.z;
      acc.w += a * w.w;
    }
    __syncthreads();
  }

  if (partial) {
    float* outp = C + ((size_t)z * 16 + b) * N + nb + jq;
    *(float4*)outp = acc;
  } else {
    int col = nb + jq;
    if (bias1) {
      acc.x += bias1[col]; acc.y += bias1[col + 1];
      acc.z += bias1[col + 2]; acc.w += bias1[col + 3];
    }
    if (bias2) {
      acc.x += bias2[col]; acc.y += bias2[col + 1];
      acc.z += bias2[col + 2]; acc.w += bias2[col + 3];
    }
    *(float4*)&C[(size_t)(mo + b) * ldc + col] = acc;
  }
}

// ---------------------------------------------------------------------------
// Fused attention step: one block per batch b.
//  - copies emb_table[token(b,t)] into layerin[b][0:768]
//  - scores[s] = relu(x_proj[b,s,:] + hWh[b,:]) . w2 + b2
//  - log_softmax over S
//  - context[e] = sum_s w_log[s] * x[b,s,e]  -> layerin[b][768:1536]
// hWhP holds 4 K-split partials of h2 @ Wh.
// ---------------------------------------------------------------------------
__global__ __launch_bounds__(256) void attn_step(
    const float* __restrict__ x, const float* __restrict__ x_proj,
    const float* __restrict__ hWhP, const float* __restrict__ w2,
    const float* __restrict__ b2p, const int* __restrict__ tokens,
    const float* __restrict__ emb_table, int t,
    float* __restrict__ layerin) {
  int b = blockIdx.x;
  int tid = threadIdx.x, lane = tid & 63, wv = tid >> 6;
  __shared__ float hwh[HH];
  __shared__ float w2l[HH];
  __shared__ float sc[SS];
  __shared__ float red0;

  // emb part of layer input
  int tok = tokens[b * TT + t];
  for (int e = tid; e < EE; e += 256)
    layerin[b * E2 + e] = emb_table[(size_t)tok * EE + e];

  for (int i = tid; i < HH; i += 256) {
    hwh[i] = hWhP[b * HH + i] + hWhP[16384 + b * HH + i] +
             hWhP[32768 + b * HH + i] + hWhP[49152 + b * HH + i];
    w2l[i] = w2[i];
  }
  __syncthreads();

  float b2 = b2p[0];
  for (int si = 0; si < 32; ++si) {
    int s = wv * 32 + si;
    const float* xp = x_proj + ((size_t)(b * SS + s)) * HH;
    float a = 0.f;
#pragma unroll 4
    for (int kk = 0; kk < 16; ++kk) {
      int k = lane + kk * 64;
      float v = xp[k] + hwh[k];
      v = fmaxf(v, 0.f);
      a += v * w2l[k];
    }
    for (int off = 32; off; off >>= 1) a += __shfl_xor(a, off);
    if (lane == 0) sc[s] = a + b2;
  }
  __syncthreads();

  if (wv == 0) {
    float m = fmaxf(sc[lane], sc[lane + 64]);
    for (int off = 32; off; off >>= 1) m = fmaxf(m, __shfl_xor(m, off));
    float e = expf(sc[lane] - m) + expf(sc[lane + 64] - m);
    for (int off = 32; off; off >>= 1) e += __shfl_xor(e, off);
    if (lane == 0) red0 = m + logf(e);
  }
  __syncthreads();
  float lse = red0;
  for (int i = tid; i < SS; i += 256) sc[i] -= lse;
  __syncthreads();

  // context with LOG-weights (faithful to the reference)
  for (int e = tid; e < EE; e += 256) {
    float acc = 0.f;
#pragma unroll 4
    for (int s = 0; s < SS; ++s)
      acc += sc[s] * x[((size_t)(b * SS + s)) * EE + e];
    layerin[b * E2 + EE + e] = acc;
  }
}

// ---------------------------------------------------------------------------
// LSTM cell update: sums 8 K-split gate partials + biases, applies gates.
// gates layout per (b): [i(0:1024) f(1024:2048) g(2048:3072) o(3072:4096)]
// ---------------------------------------------------------------------------
__global__ __launch_bounds__(256) void lstm_cell(
    const float* __restrict__ P, int nparts,
    const float* __restrict__ bi, const float* __restrict__ bh,
    float* __restrict__ h, float* __restrict__ c,
    float* __restrict__ h2out) {
  int idx = blockIdx.x * 256 + threadIdx.x;  // 0..16383
  int b = idx >> 10, j = idx & 1023;
  float g[4];
#pragma unroll
  for (int gi = 0; gi < 4; ++gi) {
    int r = gi * HH + j;
    float v = bi[r] + bh[r];
    for (int z = 0; z < nparts; ++z) v += P[(size_t)z * (BB * H4) + b * H4 + r];
    g[gi] = v;
  }
  float ig = 1.f / (1.f + expf(-g[0]));
  float fg = 1.f / (1.f + expf(-g[1]));
  float gg = tanhf(g[2]);
  float og = 1.f / (1.f + expf(-g[3]));
  float cn = fg * c[idx] + ig * gg;
  float hn = og * tanhf(cn);
  c[idx] = cn;
  h[idx] = hn;
  if (h2out) h2out[idx] = hn;
}

// ---------------------------------------------------------------------------
// fc GEMM: out[(b*T+t)*V + n] = h2all[t*B+b, :] . fc_W[n, :] + fc_b[n]
// Tile 128(m) x 64(n), K-chunk 32, 256 threads, 8x4 micro-tile per thread.
// ---------------------------------------------------------------------------
__global__ __launch_bounds__(256) void fc_gemm(
    const float* __restrict__ A,   // (1024,1024) rows m = t*16+b
    const float* __restrict__ W,   // (32000,1024)
    const float* __restrict__ bias,
    float* __restrict__ out) {
  int nb = blockIdx.x * 64;
  int mb = blockIdx.y * 128;
  __shared__ float At[32][132];  // [k][m]
  __shared__ float Wt[32][68];   // [k][n]
  int tid = threadIdx.x;
  int tx = tid & 15, ty = tid >> 4;
  float acc[8][4] = {{0.f}};

  for (int kc = 0; kc < 1024; kc += 32) {
    for (int idx = tid; idx < 128 * 32; idx += 256) {
      int r = idx >> 5, k = idx & 31;
      At[k][r] = A[(size_t)(mb + r) * 1024 + kc + k];
    }
    for (int idx = tid; idx < 64 * 32; idx += 256) {
      int r = idx >> 5, k = idx & 31;
      Wt[k][r] = W[(size_t)(nb + r) * 1024 + kc + k];
    }
    __syncthreads();
#pragma unroll 8
    for (int k = 0; k < 32; ++k) {
      float4 a0 = *(const float4*)&At[k][ty * 8];
      float4 a1 = *(const float4*)&At[k][ty * 8 + 4];
      float4 w = *(const float4*)&Wt[k][tx * 4];
      float av[8] = {a0.x, a0.y, a0.z, a0.w, a1.x, a1.y, a1.z, a1.w};
#pragma unroll
      for (int i = 0; i < 8; ++i) {
        acc[i][0] += av[i] * w.x;
        acc[i][1] += av[i] * w.y;
        acc[i][2] += av[i] * w.z;
        acc[i][3] += av[i] * w.w;
      }
    }
    __syncthreads();
  }

  float4 bv = *(const float4*)&bias[nb + tx * 4];
#pragma unroll
  for (int i = 0; i < 8; ++i) {
    int m = mb + ty * 8 + i;
    int orow = (m & 15) * TT + (m >> 4);  // (b,t) -> output row
    float4 v;
    v.x = acc[i][0] + bv.x;
    v.y = acc[i][1] + bv.y;
    v.z = acc[i][2] + bv.z;
    v.w = acc[i][3] + bv.w;
    *(float4*)&out[(size_t)orow * VV + nb + tx * 4] = v;
  }
}

// ---------------------------------------------------------------------------
// In-place log_softmax over rows of 32000
// ---------------------------------------------------------------------------
__global__ __launch_bounds__(256) void logsoftmax_rows(float* __restrict__ out) {
  size_t row = blockIdx.x;
  float* p = out + row * VV;
  __shared__ float rbuf[4];
  __shared__ float rM, rL;
  int tid = threadIdx.x, lane = tid & 63, wv = tid >> 6;

  float m = -INFINITY;
  for (int i = tid; i < VV; i += 256) m = fmaxf(m, p[i]);
  for (int off = 32; off; off >>= 1) m = fmaxf(m, __shfl_xor(m, off));
  if (lane == 0) rbuf[wv] = m;
  __syncthreads();
  if (tid == 0) rM = fmaxf(fmaxf(rbuf[0], rbuf[1]), fmaxf(rbuf[2], rbuf[3]));
  __syncthreads();
  float M = rM;

  float s = 0.f;
  for (int i = tid; i < VV; i += 256) s += expf(p[i] - M);
  for (int off = 32; off; off >>= 1) s += __shfl_xor(s, off);
  if (lane == 0) rbuf[wv] = s;
  __syncthreads();
  if (tid == 0) rL = M + logf(rbuf[0] + rbuf[1] + rbuf[2] + rbuf[3]);
  __syncthreads();
  float L = rL;
  for (int i = tid; i < VV; i += 256) p[i] -= L;
}

// ---------------------------------------------------------------------------
extern "C" void kernel_launch(void* const* d_in, const int* in_sizes, int n_in,
                              void* d_out, int out_size, void* d_ws, size_t ws_size,
                              hipStream_t stream) {
  const float* x = (const float*)d_in[0];
  const int* tokens = (const int*)d_in[1];
  const float* embtab = (const float*)d_in[2];
  const float* Wx = (const float*)d_in[3];
  const float* Wh = (const float*)d_in[4];
  const float* b1 = (const float*)d_in[5];
  const float* w2 = (const float*)d_in[6];
  const float* b2 = (const float*)d_in[7];
  const float* fcW = (const float*)d_in[8];
  const float* fcb = (const float*)d_in[9];
  const float* Wih[3] = {(const float*)d_in[10], (const float*)d_in[14], (const float*)d_in[18]};
  const float* Whh[3] = {(const float*)d_in[11], (const float*)d_in[15], (const float*)d_in[19]};
  const float* bih[3] = {(const float*)d_in[12], (const float*)d_in[16], (const float*)d_in[20]};
  const float* bhh[3] = {(const float*)d_in[13], (const float*)d_in[17], (const float*)d_in[21]};

  float* ws = (float*)d_ws;
  float* x_proj = ws;                 // 2097152  (B*S, H)
  float* WxT = x_proj + 2097152;      // 786432   (H, E)
  float* WhT = WxT + 786432;          // 1048576  (H, H)
  float* h = WhT + 1048576;           // 49152    (3, B, H)
  float* c = h + 49152;               // 49152
  float* hWhP = c + 49152;            // 65536    (4, B, H) K-split partials
  float* lin = hWhP + 65536;          // 24576    (B, 2E)
  float* gP = lin + 24576;            // 524288   (8, B, 4H) gate partials
  float* h2a = gP + 524288;           // 1048576  (T*B, H)
  float* out = (float*)d_out;

  // zero initial h, c (ws is poisoned before every call)
  hipMemsetAsync(h, 0, (size_t)(49152 + 49152) * sizeof(float), stream);

  // weight transposes for coalesced A@W^T form
  transpose_k<<<dim3(1024 / 32, 768 / 32), dim3(32, 8), 0, stream>>>(Wx, WxT, 768, 1024);
  transpose_k<<<dim3(1024 / 32, 1024 / 32), dim3(32, 8), 0, stream>>>(Wh, WhT, 1024, 1024);

  // x_proj = x @ Wx + b1   (2048 x 1024, K=768)
  gemm16<<<dim3(16, 128, 1), 256, 0, stream>>>(
      x, 768, 768, WxT, 768, 1,
      nullptr, 0, 1024, nullptr, 0, 1,
      b1, nullptr, x_proj, 1024, 1024, 0);

  float* h0 = h;
  float* h1 = h + 16384;
  float* h2 = h + 32768;
  float* c0 = c;
  float* c1 = c + 16384;
  float* c2 = c + 32768;

  for (int t = 0; t < TT; ++t) {
    // hWh partials: h2 @ Wh  (K-split 4)
    gemm16<<<dim3(16, 1, 4), 256, 0, stream>>>(
        h2, 1024, 1024, WhT, 1024, 4,
        nullptr, 0, 1024, nullptr, 0, 1,
        nullptr, nullptr, hWhP, 0, 1024, 1);

    attn_step<<<16, 256, 0, stream>>>(x, x_proj, hWhP, w2, b2, tokens, embtab, t, lin);

    // Layer 0: gates = layerin @ Wih0^T + h0 @ Whh0^T
    gemm16<<<dim3(64, 1, 8), 256, 0, stream>>>(
        lin, 1536, 1536, Wih[0], 1536, 4,
        h0, 1024, 1024, Whh[0], 1024, 4,
        nullptr, nullptr, gP, 0, 4096, 1);
    lstm_cell<<<64, 256, 0, stream>>>(gP, 8, bih[0], bhh[0], h0, c0, nullptr);

    // Layer 1
    gemm16<<<dim3(64, 1, 8), 256, 0, stream>>>(
        h0, 1024, 1024, Wih[1], 1024, 4,
        h1, 1024, 1024, Whh[1], 1024, 4,
        nullptr, nullptr, gP, 0, 4096, 1);
    lstm_cell<<<64, 256, 0, stream>>>(gP, 8, bih[1], bhh[1], h1, c1, nullptr);

    // Layer 2 (also records h2 into h2all[t])
    gemm16<<<dim3(64, 1, 8), 256, 0, stream>>>(
        h1, 1024, 1024, Wih[2], 1024, 4,
        h2, 1024, 1024, Whh[2], 1024, 4,
        nullptr, nullptr, gP, 0, 4096, 1);
    lstm_cell<<<64, 256, 0, stream>>>(gP, 8, bih[2], bhh[2], h2, c2, h2a + t * 16384);
  }

  // final projection + log_softmax
  fc_gemm<<<dim3(VV / 64, 1024 / 128), 256, 0, stream>>>(h2a, fcW, fcb, out);
  logsoftmax_rows<<<BB * TT, 256, 0, stream>>>(out);
}